// Round 11
// baseline (156.463 us; speedup 1.0000x reference)
//
#include <hip/hip_runtime.h>

typedef __attribute__((ext_vector_type(8))) short short8;
typedef __attribute__((ext_vector_type(4))) short short4v;
typedef __attribute__((ext_vector_type(4))) float float4v;
typedef __attribute__((ext_vector_type(4))) unsigned int uint4v;

typedef const void __attribute__((address_space(1)))* gptr_t;
typedef void __attribute__((address_space(3)))* lptr_t;

__device__ __forceinline__ void gload_lds16(const void* g, void* l) {
    __builtin_amdgcn_global_load_lds((gptr_t)g, (lptr_t)l, 16, 0, 0);
}

__device__ __forceinline__ unsigned short f2bf(float f) {
    union { float f; unsigned int u; } v; v.f = f;
    unsigned int r = v.u + 0x7fffu + ((v.u >> 16) & 1u);
    return (unsigned short)(r >> 16);
}

__device__ __forceinline__ short8 frag_ld(const unsigned char* base, int row, int k2) {
    return *(const short8*)(base + row * 128 + (k2 ^ ((row & 7) << 4)));
}

__device__ __forceinline__ float4v mfma_bf16(short8 a, short8 b, float4v c) {
    return __builtin_amdgcn_mfma_f32_16x16x32_bf16(a, b, c, 0, 0, 0);
}

// fp8 tile row-swizzle term: spreads the 4 16B chunks of a 64B row
__device__ __forceinline__ int xsw(int r) {
    return (r & 3) ^ ((r >> 2) & 3);
}

// pack 4 f32 -> 4 fp8 (e4m3, RNE) in a u32
__device__ __forceinline__ unsigned int pk4_fp8(float a, float b, float c, float d) {
    int w = __builtin_amdgcn_cvt_pk_fp8_f32(a, b, 0, false);
    w = __builtin_amdgcn_cvt_pk_fp8_f32(c, d, w, true);
    return (unsigned int)w;
}

// out[a][b] = bf16(in[b][a]), 1024x1024
__global__ __launch_bounds__(256) void k_transpose_bf16(
        const float* __restrict__ in, unsigned short* __restrict__ out) {
    __shared__ float tile[32][33];
    int tx = threadIdx.x, ty = threadIdx.y;
    int x = blockIdx.x * 32 + tx;
    int ybase = blockIdx.y * 32;
#pragma unroll
    for (int j = 0; j < 4; j++)
        tile[ty + j * 8][tx] = in[(size_t)(ybase + ty + j * 8) * 1024 + x];
    __syncthreads();
    int ox = ybase + tx;
    int oybase = blockIdx.x * 32;
#pragma unroll
    for (int j = 0; j < 4; j++)
        out[(size_t)(oybase + ty + j * 8) * 1024 + ox] = f2bf(tile[tx][ty + j * 8]);
}

// peA8[pix][ic] = fp8(8 * W_emb[ic][pix])  (1 MB, plain layout)
__global__ __launch_bounds__(256) void k_prep_A(
        const float* __restrict__ W_emb, unsigned int* __restrict__ peA8) {
    __shared__ float tile[32][33];
    int tx = threadIdx.x, ty = threadIdx.y;
    int icb = blockIdx.y * 32, pixb = blockIdx.x * 32;
#pragma unroll
    for (int j = 0; j < 4; j++)
        tile[ty + j * 8][tx] = W_emb[(size_t)(icb + ty + j * 8) * 1024 + pixb + tx];
    __syncthreads();
    int u = tx & 7;                 // ic quad within the 32-ic block
    int pix_l = (tx >> 3) * 8 + ty; // 0..31
    unsigned int w = pk4_fp8(8.f * tile[u * 4 + 0][pix_l], 8.f * tile[u * 4 + 1][pix_l],
                             8.f * tile[u * 4 + 2][pix_l], 8.f * tile[u * 4 + 3][pix_l]);
    peA8[(size_t)(pixb + pix_l) * 256 + (icb >> 2) + u] = w;
}

// Stream conv_w (FULL-ROW contiguous reads) -> fp8 x8 panels in the conv's exact
// LDS image layout. Panel (s,nt) = 16 steps x 8KB; image byte for (n, k-chunk cq)
// lives at n*64 + ((cq ^ xsw(n))*16). Block = (s, step, ocg=512-col group).
__global__ __launch_bounds__(256) void k_prep_B(
        const float* __restrict__ convw,          // [9216][4096]
        unsigned char* __restrict__ Bp) {
    __shared__ float ldsF[16 * 516];
    const int t = threadIdx.x;
    const int p = blockIdx.x;                     // 1152 = 9*16*8
    const int ocg  = p & 7;
    const int step = (p >> 3) & 15;
    const int s    = p >> 7;
    const int kbase = s * 1024 + step * 64;
    const int cbase = ocg * 512;

    for (int it = 0; it < 4; it++) {              // 16 k-rows at a time
#pragma unroll
        for (int j = 0; j < 8; j++) {
            int idx = j * 256 + t;
            int r = idx >> 7, qc = idx & 127;
            float4v v = *(const float4v*)(convw
                + (size_t)(kbase + it * 16 + r) * 4096 + cbase + qc * 4);
            *(float4v*)(&ldsF[r * 516 + qc * 4]) = v;
        }
        __syncthreads();
#pragma unroll
        for (int h = 0; h < 2; h++) {
            int n = h * 256 + t;                  // 0..511 within col group
            float f[16];
#pragma unroll
            for (int k = 0; k < 16; k++) f[k] = 8.f * ldsF[k * 516 + n];
            uint4v wv;
            wv.x = pk4_fp8(f[0], f[1], f[2], f[3]);
            wv.y = pk4_fp8(f[4], f[5], f[6], f[7]);
            wv.z = pk4_fp8(f[8], f[9], f[10], f[11]);
            wv.w = pk4_fp8(f[12], f[13], f[14], f[15]);
            int gcol = cbase + n;
            int nt = gcol >> 7, nl = gcol & 127;
            unsigned char* dst = Bp + ((size_t)((s * 32 + nt) * 16 + step) << 13)
                               + nl * 64 + ((it ^ xsw(nl)) << 4);
            *(uint4v*)dst = wv;
        }
        __syncthreads();
    }
}

// fp8 conv-GEMM: tile 128m x 128n, wave 64x64, K-step 64 (2 mfma/acc).
// BOTH operands staged LINEARLY via global_load_lds. 2-deep vmcnt pipeline.
__global__ __launch_bounds__(256, 4) void k_conv_f8(
        const unsigned char* __restrict__ peA8,   // [1024 pix][1024 ic] fp8
        const unsigned char* __restrict__ zerobuf,
        const unsigned char* __restrict__ Bp,
        float* __restrict__ y_acc)                // [256][4096]
{
    __shared__ __align__(16) unsigned char ldsA[2][8192]; // [128 m][64 k] fp8 swz
    __shared__ __align__(16) unsigned char ldsB[2][8192]; // [128 n][64 k] fp8 swz

    const int t = threadIdx.x;
    const int L = blockIdx.x;                     // 576 = 8*72
    const int ell = (L & 7) * 72 + (L >> 3);
    const int mt = ell & 1;
    const int nt = (ell >> 1) & 31;
    const int s  = ell >> 6;
    const int kh = s / 3, kw = s - kh * 3;
    const int ncol0 = nt * 128;

    const int l = t & 63, w = t >> 6;
    const int wm = w >> 1, wn = w & 1;            // wave tile 64m x 64n
    const int l15 = l & 15;
    const int k8 = l >> 4;                        // 0..3
    const int hh = (k8 & 1) * 8;

    float4v acc[4][4] = {};

    const unsigned char* asrc[2];
    int aok[2];
#pragma unroll
    for (int i = 0; i < 2; i++) {
        int q = i * 256 + t;                      // 0..511
        int r = q >> 2, cslot = q & 3;
        int cq = cslot ^ xsw(r);
        int m = mt * 128 + r;
        int oh = m >> 4, ow = m & 15;
        int ih = 2 * oh + kh, iw = 2 * ow + kw;
        bool ok = (ih < 32) && (iw < 32);
        asrc[i] = ok ? (peA8 + (size_t)(ih * 32 + iw) * 1024 + cq * 16) : zerobuf;
        aok[i] = ok ? ~0 : 0;
    }
    const unsigned char* panel = Bp + ((size_t)((s * 32 + nt) * 16) << 13);

#pragma unroll
    for (int i = 0; i < 2; i++) {
        int q = i * 256 + t;
        gload_lds16(asrc[i], &ldsA[0][q * 16]);
        gload_lds16(panel + q * 16, &ldsB[0][q * 16]);
    }
    __builtin_amdgcn_sched_barrier(0);
#pragma unroll
    for (int i = 0; i < 2; i++) {
        int q = i * 256 + t;
        gload_lds16(asrc[i] + (64 & aok[i]), &ldsA[1][q * 16]);
        gload_lds16(panel + 8192 + q * 16, &ldsB[1][q * 16]);
    }
    asm volatile("s_waitcnt vmcnt(4)" ::: "memory");
    __builtin_amdgcn_sched_barrier(0);
    __builtin_amdgcn_s_barrier();

#pragma unroll
    for (int tt = 0; tt < 16; ++tt) {
        const int cur = tt & 1;

        long af[4][2], bfr[4][2];
#pragma unroll
        for (int mf = 0; mf < 4; mf++)
#pragma unroll
            for (int ks = 0; ks < 2; ks++) {
                int r = wm * 64 + mf * 16 + l15;
                int cq = ks * 2 + (k8 >> 1);
                af[mf][ks] = *(const long*)(&ldsA[cur][r * 64 + ((cq ^ xsw(r)) * 16) + hh]);
            }
#pragma unroll
        for (int nf = 0; nf < 4; nf++)
#pragma unroll
            for (int ks = 0; ks < 2; ks++) {
                int n = wn * 64 + nf * 16 + l15;
                int cq = ks * 2 + (k8 >> 1);
                bfr[nf][ks] = *(const long*)(&ldsB[cur][n * 64 + ((cq ^ xsw(n)) * 16) + hh]);
            }
        asm volatile("s_waitcnt lgkmcnt(0)" ::: "memory");
        __builtin_amdgcn_sched_barrier(0);
        __builtin_amdgcn_s_barrier();
        __builtin_amdgcn_sched_barrier(0);

        if (tt < 14) {
            const int k0n = (tt + 2) * 64;
#pragma unroll
            for (int i = 0; i < 2; i++) {
                int q = i * 256 + t;
                gload_lds16(asrc[i] + (k0n & aok[i]), &ldsA[cur][q * 16]);
                gload_lds16(panel + (tt + 2) * 8192 + q * 16, &ldsB[cur][q * 16]);
            }
        }

        __builtin_amdgcn_s_setprio(1);
#pragma unroll
        for (int mf = 0; mf < 4; mf++)
#pragma unroll
            for (int nf = 0; nf < 4; nf++)
#pragma unroll
                for (int ks = 0; ks < 2; ks++)
                    acc[mf][nf] = __builtin_amdgcn_mfma_f32_16x16x32_fp8_fp8(
                        af[mf][ks], bfr[nf][ks], acc[mf][nf], 0, 0, 0);
        __builtin_amdgcn_s_setprio(0);

        if (tt < 15) {
            if (tt < 14) asm volatile("s_waitcnt vmcnt(4)" ::: "memory");
            else         asm volatile("s_waitcnt vmcnt(0)" ::: "memory");
            __builtin_amdgcn_sched_barrier(0);
            __builtin_amdgcn_s_barrier();
        }
    }

#pragma unroll
    for (int mf = 0; mf < 4; mf++) {
        int row = mt * 128 + wm * 64 + mf * 16 + (l >> 4) * 4;
#pragma unroll
        for (int nf = 0; nf < 4; nf++) {
            int col = ncol0 + wn * 64 + nf * 16 + l15;
#pragma unroll
            for (int r = 0; r < 4; r++)
                atomicAdd(&y_acc[(size_t)(row + r) * 4096 + col], acc[mf][nf][r]);
        }
    }
}

// bias + BN + LeakyReLU; y was computed with x8-scaled fp8 inputs -> /64
__global__ __launch_bounds__(256) void k_bn_pos2(
        const float* __restrict__ y_acc, const float* __restrict__ cb,
        const float* __restrict__ gamma, const float* __restrict__ beta,
        const float* __restrict__ mean, const float* __restrict__ var,
        float* __restrict__ pos2img) {
    int idx = blockIdx.x * 256 + threadIdx.x;   // [m=256][oc=4096]
    int m = idx >> 12, oc = idx & 4095;
    float v = y_acc[idx] * 0.015625f + cb[oc];
    v = (v - mean[oc]) * (gamma[oc] * rsqrtf(var[oc] + 1e-3f)) + beta[oc];
    v = v > 0.0f ? v : 0.3f * v;
    int y = ((oc >> 6) << 4) + (m >> 4);
    int x = ((oc & 63) << 4) + (m & 15);
    pos2img[y * 1024 + x] = v;
}

// enc0[b,n0,d0] = X[b,y,x] + pos2img[y,x] + W_emb[n0,d0], cast bf16
__global__ __launch_bounds__(256) void k_build_A(
        const float* __restrict__ X, const float* __restrict__ pos2img,
        const float* __restrict__ W_emb, unsigned short* __restrict__ Aenc) {
    int row = blockIdx.x;            // b*1024 + n0
    int n0 = row & 1023;
    int b  = row >> 10;
    int d0 = threadIdx.x * 4;
    int y = ((n0 >> 5) << 5) + (d0 >> 5);
    int x = ((n0 & 31) << 5) + (d0 & 31);
    size_t pix = (size_t)y * 1024 + x;
    float4v xv = *(const float4v*)(X + (size_t)b * 1048576 + pix);
    float4v pv = *(const float4v*)(pos2img + pix);
    float4v wv = *(const float4v*)(W_emb + (size_t)n0 * 1024 + d0);
    short4v o;
    o.x = (short)f2bf(xv.x + pv.x + wv.x);
    o.y = (short)f2bf(xv.y + pv.y + wv.y);
    o.z = (short)f2bf(xv.z + pv.z + wv.z);
    o.w = (short)f2bf(xv.w + pv.w + wv.w);
    *(short4v*)(Aenc + (size_t)row * 1024 + d0) = o;
}

// C[8192][1024] = A[8192][1024] * W_dense[1024][1024] + bias, bf16 MFMA
__global__ __launch_bounds__(256) void k_final_gemm(
        const unsigned short* __restrict__ A,
        const unsigned short* __restrict__ Bt,
        const float* __restrict__ bias,
        float* __restrict__ C) {
    __shared__ __align__(16) unsigned char ldsA[16384];
    __shared__ __align__(16) unsigned char ldsB[16384];
    const int t = threadIdx.x;
    const int L = blockIdx.x;
    const int ell = (L & 7) * 64 + (L >> 3);
    const int col0 = (ell & 7) * 128;
    const int row0 = (ell >> 3) * 128;
    const int l = t & 63, w = t >> 6;
    const int wm = w >> 1, wn = w & 1;
    const int l15 = l & 15;
    const int lk2 = (l >> 4) * 16;

    float4v acc[4][4] = {};

    const unsigned short* asrc[4];
    const unsigned short* bsrc[4];
#pragma unroll
    for (int i = 0; i < 4; i++) {
        int idx = i * 256 + t;
        int r = idx >> 3, c8 = idx & 7;
        int cofs = (c8 ^ (r & 7)) * 8;
        asrc[i] = A  + (size_t)(row0 + r) * 1024 + cofs;
        bsrc[i] = Bt + (size_t)(col0 + r) * 1024 + cofs;
    }

    for (int k0 = 0; k0 < 1024; k0 += 64) {
#pragma unroll
        for (int i = 0; i < 4; i++) {
            int idx = i * 256 + t;
            gload_lds16(asrc[i] + k0, ldsA + idx * 16);
            gload_lds16(bsrc[i] + k0, ldsB + idx * 16);
        }
        __syncthreads();

        short8 af[4][2], bfr[4][2];
#pragma unroll
        for (int mf = 0; mf < 4; mf++)
#pragma unroll
            for (int ks = 0; ks < 2; ks++)
                af[mf][ks] = frag_ld(ldsA, wm * 64 + mf * 16 + l15, ks * 64 + lk2);
#pragma unroll
        for (int nf = 0; nf < 4; nf++)
#pragma unroll
            for (int ks = 0; ks < 2; ks++)
                bfr[nf][ks] = frag_ld(ldsB, wn * 64 + nf * 16 + l15, ks * 64 + lk2);
#pragma unroll
        for (int mf = 0; mf < 4; mf++)
#pragma unroll
            for (int nf = 0; nf < 4; nf++)
#pragma unroll
                for (int ks = 0; ks < 2; ks++)
                    acc[mf][nf] = mfma_bf16(af[mf][ks], bfr[nf][ks], acc[mf][nf]);
        __syncthreads();
    }

#pragma unroll
    for (int nf = 0; nf < 4; nf++) {
        int col = col0 + wn * 64 + nf * 16 + l15;
        float bv = bias[col];
#pragma unroll
        for (int mf = 0; mf < 4; mf++) {
            int row = row0 + wm * 64 + mf * 16 + (l >> 4) * 4;
#pragma unroll
            for (int r = 0; r < 4; r++)
                C[(size_t)(row + r) * 1024 + col] = acc[mf][nf][r] + bv;
        }
    }
}

extern "C" void kernel_launch(void* const* d_in, const int* in_sizes, int n_in,
                              void* d_out, int out_size, void* d_ws, size_t ws_size,
                              hipStream_t stream) {
    (void)in_sizes; (void)n_in; (void)out_size; (void)ws_size;
    const float* X       = (const float*)d_in[0];
    const float* W_emb   = (const float*)d_in[1];
    const float* conv_w  = (const float*)d_in[2];
    const float* conv_b  = (const float*)d_in[3];
    const float* gamma   = (const float*)d_in[4];
    const float* beta    = (const float*)d_in[5];
    const float* mean    = (const float*)d_in[6];
    const float* var     = (const float*)d_in[7];
    const float* W_dense = (const float*)d_in[8];
    const float* b_dense = (const float*)d_in[9];
    float* out = (float*)d_out;

    const size_t MB = 1u << 20;
    unsigned char* ws = (unsigned char*)d_ws;
    float*          y_acc   = (float*)(ws);                      // 4 MB
    unsigned char*  zerobuf = ws + 4 * MB;                       // 4 KB (memset)
    unsigned int*   peA8    = (unsigned int*)(ws + 5 * MB);      // 1 MB fp8
    unsigned char*  Bp      = ws + 8 * MB;                       // 36.9 MB fp8 panels
    // overlays over Bp (used only after conv completes):
    float*          pos2img = (float*)(ws + 8 * MB);             // 4 MB
    unsigned short* Aenc    = (unsigned short*)(ws + 12 * MB);   // 16 MB
    unsigned short* WdT     = (unsigned short*)(ws + 28 * MB);   // 2 MB

    hipMemsetAsync(y_acc, 0, 4 * MB + 4096, stream);

    dim3 tb(32, 8);
    k_prep_A<<<dim3(32, 32), tb, 0, stream>>>(W_emb, peA8);
    k_prep_B<<<1152, 256, 0, stream>>>(conv_w, Bp);
    k_conv_f8<<<576, 256, 0, stream>>>((const unsigned char*)peA8, zerobuf, Bp, y_acc);
    k_bn_pos2<<<4096, 256, 0, stream>>>(y_acc, conv_b, gamma, beta, mean, var, pos2img);
    k_build_A<<<8192, 256, 0, stream>>>(X, pos2img, W_emb, Aenc);
    k_transpose_bf16<<<dim3(32, 32), tb, 0, stream>>>(W_dense, WdT);
    k_final_gemm<<<512, 256, 0, stream>>>(Aenc, WdT, b_dense, out);
}